// Round 2
// baseline (405.150 us; speedup 1.0000x reference)
//
#include <hip/hip_runtime.h>

// x: (64,3,512,512) fp32 -> conv3x3 VALID + avgpool2x2 + sigmoid + per-batch sum.
// Fused stride-2 4x4 conv: w_eff[ky][kx] = 0.25*sum_{py,px in {0,1}} w[ky-py][kx-px].
//
// R3 structure: ROW STREAMING. Thread = one pooled col (4 input cols). Stream the
// strip's 12 input rows; keep TWO pending pooled rows as packed v2f accumulators
// {old, new} per oc (32 VGPRs). Per input row: 6 coalesced dwordx2 loads (double-
// buffered one row ahead) + 12 taps x { s_load of 16 weight PAIRS (SGPRs),
// 16 v_pk_fma_f32 }. No x re-loads, no per-oc stall chain, ~70 VGPRs.
// (R3b: launch_bounds min-waves 6 -> 4; 85-VGPR cap risked scratch spills.)

#define IC 3
#define OCH 16
#define HH 512
#define WW 512
#define WP 255      // pooled cols
#define L 5         // pooled rows per strip
#define STRIPS 51   // 51 * 5 = 255 pooled rows

typedef float v2f __attribute__((ext_vector_type(2)));

__device__ __forceinline__ float fast_sigmoid(float v) {
    float e = __expf(-v);                    // v_exp_f32
    return __builtin_amdgcn_rcpf(1.0f + e);  // v_rcp_f32
}

// ws layout (floats):
//   pair table: p = ((kyp*IC + ic)*4 + kx)*16 + oc   (kyp in {0,1}; 384 pairs)
//     ws[2p]   = w_eff[kyp+2][ic][kx] (oc)   -> acc.x ("old" pending pooled row)
//     ws[2p+1] = w_eff[kyp  ][ic][kx] (oc)   -> acc.y ("new" pending pooled row)
//   bias: ws[768 + oc]
// Total 784 floats = 3136 B.
__global__ void build_weff(const float* __restrict__ w,
                           const float* __restrict__ bias,
                           float* __restrict__ ws)
{
    const int i = threadIdx.x;
    for (int idx = i; idx < 384; idx += 256) {
        const int oc  = idx & 15;
        const int tap = idx >> 4;        // (kyp*3+ic)*4+kx
        const int kx  = tap & 3;
        const int t2  = tap >> 2;        // kyp*3+ic
        const int kyp = t2 / 3;
        const int ic  = t2 - kyp * 3;
        float s[2];
#pragma unroll
        for (int which = 0; which < 2; ++which) {
            const int ky = which ? kyp : kyp + 2;   // which=0: old (ky+2), 1: new
            float acc = 0.f;
#pragma unroll
            for (int py = 0; py < 2; ++py) {
                int r = ky - py;
                if (r < 0 || r > 2) continue;
#pragma unroll
                for (int px = 0; px < 2; ++px) {
                    int c = kx - px;
                    if (c < 0 || c > 2) continue;
                    acc += w[((oc * IC + ic) * 3 + r) * 3 + c];
                }
            }
            s[which] = 0.25f * acc;
        }
        ws[2 * idx]     = s[0];
        ws[2 * idx + 1] = s[1];
    }
    if (i < OCH) ws[768 + i] = bias[i];
}

#define LOADROW(buf, q)                                                  \
    {                                                                    \
        _Pragma("unroll")                                                \
        for (int ic_ = 0; ic_ < IC; ++ic_) {                             \
            const float* p_ = xb + (size_t)ic_ * (HH * WW)               \
                                 + (size_t)(q) * WW;                     \
            buf[ic_][0] = *(const v2f*)p_;                               \
            buf[ic_][1] = *(const v2f*)(p_ + 2);                         \
        }                                                                \
    }

// One input row's contribution: 12 taps, each = 16 weight-pairs * broadcast xv.
#define TAPS(buf, kyp)                                                   \
    {                                                                    \
        _Pragma("unroll")                                                \
        for (int ic_ = 0; ic_ < IC; ++ic_) {                             \
            _Pragma("unroll")                                            \
            for (int kx_ = 0; kx_ < 4; ++kx_) {                          \
                const float xv_ = (kx_ < 2) ? buf[ic_][0][kx_]           \
                                            : buf[ic_][1][kx_ - 2];      \
                const v2f* wp_ = wtab + (((kyp) * IC + ic_) * 4 + kx_) * 16; \
                _Pragma("unroll")                                        \
                for (int oc_ = 0; oc_ < OCH; ++oc_)                      \
                    acc[oc_] += wp_[oc_] * xv_;                          \
            }                                                            \
        }                                                                \
    }

__global__ __launch_bounds__(256, 4)
void conv_pool_sig_sum(const float* __restrict__ x,
                       const float* __restrict__ ws,
                       float* __restrict__ out)
{
    const int tid = threadIdx.x;              // 0..255; thread = pooled col
    const int j = (tid < WP) ? tid : WP - 1;  // clamp lane 255 (masked later)
    const int b = blockIdx.y;
    const int r0 = blockIdx.x * L;            // first pooled row of strip

    const v2f* __restrict__ wtab = (const v2f*)ws;
    const float* __restrict__ bs = ws + 768;

    // Strip base: image rows 2*r0 .. 2*r0+11, cols 2j..2j+3 per thread.
    const float* xb = x + (size_t)b * IC * HH * WW
                        + (size_t)(2 * r0) * WW + 2 * j;

    v2f xA[IC][2], xB[IC][2];   // even-row / odd-row double buffers
    LOADROW(xA, 0)
    LOADROW(xB, 1)

    // acc[oc] = {old pending pooled row, new pending pooled row}
    v2f acc[OCH];
#pragma unroll
    for (int oc = 0; oc < OCH; ++oc) acc[oc] = (v2f){0.f, 0.f};

    float lsum = 0.f;

#pragma unroll 1
    for (int t = 0; t <= L; ++t) {
        // rotate: new becomes old; new pending starts at bias.
        // (t=0: old slot gets garbage, discarded at t=1 rotate. t=L: new slot
        //  garbage, never read. Boundary rows thus need no branches.)
#pragma unroll
        for (int oc = 0; oc < OCH; ++oc) {
            acc[oc].x = acc[oc].y;
            acc[oc].y = bs[oc];
        }

        // even input row 2t: old gets ky=2, new gets ky=0  (kyp=0 pair table)
        TAPS(xA, 0)
        { const int qa = (2 * t + 2 <= 2 * L + 1) ? (2 * t + 2) : (2 * L + 1);
          LOADROW(xA, qa) }   // prefetch next even row (clamped; tail load dead)

        // odd input row 2t+1: old gets ky=3, new gets ky=1  (kyp=1 pair table)
        TAPS(xB, 1)
        { const int qb = (2 * t + 3 <= 2 * L + 1) ? (2 * t + 3) : (2 * L + 1);
          LOADROW(xB, qb) }

        if (t > 0) {   // acc.x = pooled row r0+t-1, fully accumulated
#pragma unroll
            for (int oc = 0; oc < OCH; ++oc) lsum += fast_sigmoid(acc[oc].x);
        }
    }

    if (tid >= WP) lsum = 0.f;   // drop the clamped duplicate lane

    // wave64 butterfly, one atomic per wave (4 per block)
#pragma unroll
    for (int off = 32; off > 0; off >>= 1)
        lsum += __shfl_xor(lsum, off, 64);
    if ((tid & 63) == 0) atomicAdd(out + b, lsum);
}

extern "C" void kernel_launch(void* const* d_in, const int* in_sizes, int n_in,
                              void* d_out, int out_size, void* d_ws, size_t ws_size,
                              hipStream_t stream) {
    const float* x = (const float*)d_in[0];
    const float* w = (const float*)d_in[1];
    const float* bias = (const float*)d_in[2];
    float* out = (float*)d_out;
    float* wws = (float*)d_ws;  // 784 floats = 3136 B

    hipMemsetAsync(out, 0, out_size * sizeof(float), stream);
    build_weff<<<1, 256, 0, stream>>>(w, bias, wws);

    dim3 grid(STRIPS, 64);  // 51 row-strips x 64 batches = 3264 blocks x 4 waves
    conv_pool_sig_sum<<<grid, 256, 0, stream>>>(x, wws, out);
}